// Round 1
// baseline (1034.802 us; speedup 1.0000x reference)
//
#include <hip/hip_runtime.h>

// Problem constants
#define D 4096
#define OBJ 20
#define M_MEM 1000
#define B_ 4
#define Q_ 4
#define F_ 20
// frames out = Q*B*F = 320; frame elems = OBJ*D = 81920 (=20480 float4)
// out layout: Rp [320*81920] | Rn [320*81920] | high_sim [16] | low_sim [16]
#define FRAME_F4 20480
#define RP_SZ 26214400
#define OUT_TAIL 52428800

__device__ __forceinline__ float4 f4max(float4 a, float4 b){
  return make_float4(fmaxf(a.x,b.x), fmaxf(a.y,b.y), fmaxf(a.z,b.z), fmaxf(a.w,b.w));
}
__device__ __forceinline__ float4 f4scale(float4 a, float s){
  return make_float4(a.x*s, a.y*s, a.z*s, a.w*s);
}
__device__ __forceinline__ double f4ss(float4 a){
  return (double)a.x*a.x + (double)a.y*a.y + (double)a.z*a.z + (double)a.w*a.w;
}

// 256-thread block sum reduce (f64), result broadcast to all threads
__device__ __forceinline__ double blockReduce256(double v){
  #pragma unroll
  for (int off = 32; off > 0; off >>= 1) v += __shfl_down(v, off, 64);
  __shared__ double sh[4];
  int w = threadIdx.x >> 6;
  if ((threadIdx.x & 63) == 0) sh[w] = v;
  __syncthreads();
  return sh[0] + sh[1] + sh[2] + sh[3];
}

// K1: inverse L2 norm of each (b,f,o) row of x  [1600 rows x 4096]
__global__ void k_norms(const float* __restrict__ x, float* __restrict__ inv_norm){
  int row = blockIdx.x;
  const float4* p = (const float4*)x + (size_t)row * 1024;
  double ss = 0.0;
  for (int i = threadIdx.x; i < 1024; i += 256){ float4 v = __ldg(p + i); ss += f4ss(v); }
  ss = blockReduce256(ss);
  if (threadIdx.x == 0) inv_norm[row] = (float)(1.0 / fmax(sqrt(ss), 1e-12));
}

// K2: R_max normalized rows [80 x 4096]
__global__ void k_rmax(const float* __restrict__ x, const float* __restrict__ inv_norm,
                       float* __restrict__ rmaxn){
  int bf = blockIdx.x; // 0..79
  __shared__ float sinv[OBJ];
  if (threadIdx.x < OBJ) sinv[threadIdx.x] = inv_norm[bf*OBJ + threadIdx.x];
  __syncthreads();
  float4 mv[4];
  #pragma unroll
  for (int i = 0; i < 4; i++) mv[i] = make_float4(-INFINITY,-INFINITY,-INFINITY,-INFINITY);
  const float4* base = (const float4*)x + (size_t)bf * OBJ * 1024;
  for (int o = 0; o < OBJ; o++){
    float s = sinv[o];
    const float4* p = base + o*1024;
    #pragma unroll
    for (int i = 0; i < 4; i++){
      float4 v = __ldg(p + threadIdx.x + i*256);
      mv[i] = f4max(mv[i], f4scale(v, s));
    }
  }
  double ss = 0.0;
  #pragma unroll
  for (int i = 0; i < 4; i++) ss += f4ss(mv[i]);
  ss = blockReduce256(ss);
  float rinv = (float)(1.0 / fmax(sqrt(ss), 1e-12));
  float4* outp = (float4*)rmaxn + (size_t)bf * 1024;
  #pragma unroll
  for (int i = 0; i < 4; i++) outp[threadIdx.x + i*256] = f4scale(mv[i], rinv);
}

// K3: mem max-pool over OBJ + L2 normalize -> mpn [1000 x 4096] each (the 655 MB stream)
__global__ void k_memmp(const float* __restrict__ mem1, const float* __restrict__ mem2,
                        float* __restrict__ out1, float* __restrict__ out2){
  int blk = blockIdx.x; // 0..1999
  const float* mem; float* outp; int m;
  if (blk < M_MEM){ mem = mem1; outp = out1; m = blk; }
  else            { mem = mem2; outp = out2; m = blk - M_MEM; }
  const float4* base = (const float4*)mem + (size_t)m * FRAME_F4;
  float4 mv[4];
  #pragma unroll
  for (int i = 0; i < 4; i++) mv[i] = make_float4(-INFINITY,-INFINITY,-INFINITY,-INFINITY);
  for (int o = 0; o < OBJ; o++){
    const float4* p = base + o*1024;
    #pragma unroll
    for (int i = 0; i < 4; i++) mv[i] = f4max(mv[i], __ldg(p + threadIdx.x + i*256));
  }
  double ss = 0.0;
  #pragma unroll
  for (int i = 0; i < 4; i++) ss += f4ss(mv[i]);
  ss = blockReduce256(ss);
  float rinv = (float)(1.0 / fmax(sqrt(ss), 1e-12));
  float4* o4 = (float4*)outp + (size_t)m * 1024;
  #pragma unroll
  for (int i = 0; i < 4; i++) o4[threadIdx.x + i*256] = f4scale(mv[i], rinv);
}

// K4: per (b,q): argmax frame (high) and rand-th smallest frame among the rest (low)
__global__ void k_topk(const float* __restrict__ qr, const int* __restrict__ rand_idx,
                       int* __restrict__ high_idx, int* __restrict__ low_idx){
  int t = threadIdx.x; // t = b*4+q
  if (t >= 16) return;
  float w[F_];
  for (int f = 0; f < F_; f++) w[f] = qr[t*F_ + f];
  int hi = 0; float hv = w[0];
  for (int f = 1; f < F_; f++) if (w[f] > hv){ hv = w[f]; hi = f; }
  int r = rand_idx[t];
  bool used[F_];
  for (int f = 0; f < F_; f++) used[f] = false;
  used[hi] = true;
  int li = 0;
  for (int it = 0; it <= r; it++){
    int bi = -1; float bv = INFINITY;
    for (int f = 0; f < F_; f++) if (!used[f] && w[f] < bv){ bv = w[f]; bi = f; }
    used[bi] = true; li = bi;
  }
  high_idx[t] = hi; low_idx[t] = li;
}

// K5a: dots of 80 rmaxn rows vs 4 mem_mpn rows (staged in LDS), partial argmax per chunk
__global__ void k_dots(const float* __restrict__ mpn1, const float* __restrict__ mpn2,
                       const float* __restrict__ rmaxn,
                       float* __restrict__ pvals, int* __restrict__ pidx){
  int blk = blockIdx.x;         // 0..499
  int which = blk / 250;        // 0 -> mem1, 1 -> mem2
  int chunk = blk % 250;        // 4 m-rows per chunk
  const float* mpn = which ? mpn2 : mpn1;
  __shared__ float rows[4*D];   // 64 KB
  __shared__ float pv[4][80];
  const float4* src = (const float4*)mpn + (size_t)chunk * 4 * 1024;
  float4* dst = (float4*)rows;
  for (int i = threadIdx.x; i < 4096; i += 256) dst[i] = __ldg(src + i);
  __syncthreads();
  int w = threadIdx.x >> 6, lane = threadIdx.x & 63;
  const float* mrow = rows + w*D;
  for (int bf = 0; bf < 80; bf++){
    const float* rrow = rmaxn + (size_t)bf * D;
    double acc = 0.0;
    #pragma unroll 8
    for (int i = 0; i < 64; i++)
      acc += (double)__ldg(rrow + i*64 + lane) * (double)mrow[i*64 + lane];
    #pragma unroll
    for (int off = 32; off > 0; off >>= 1) acc += __shfl_down(acc, off, 64);
    if (lane == 0) pv[w][bf] = (float)acc;
  }
  __syncthreads();
  if (threadIdx.x < 80){
    int bf = threadIdx.x;
    float best = pv[0][bf]; int bw = 0;
    #pragma unroll
    for (int w2 = 1; w2 < 4; w2++){ float v = pv[w2][bf]; if (v > best){ best = v; bw = w2; } }
    pvals[(size_t)which*20000 + chunk*80 + bf] = best;
    pidx [(size_t)which*20000 + chunk*80 + bf] = chunk*4 + bw;
  }
}

// K5b: final argmax over chunks -> sims; derive per-(b,q) memory rows + index outputs
__global__ void k_finish(const float* __restrict__ pvals, const int* __restrict__ pidx,
                         const int* __restrict__ high_idx, const int* __restrict__ low_idx,
                         int* __restrict__ rp_row, int* __restrict__ rn_row,
                         float* __restrict__ outp){
  __shared__ int ssim[160]; // sim1[80] | sim2[80]
  int t = threadIdx.x;
  if (t < 160){
    int base = (t/80)*20000 + (t%80);
    float best = -INFINITY; int bi = 0;
    for (int c = 0; c < 250; c++){
      float v = pvals[base + c*80];
      if (v > best){ best = v; bi = pidx[base + c*80]; }
    }
    ssim[t] = bi;
  }
  __syncthreads();
  if (t < 16){ // t = b*4+q
    int b = t >> 2, q = t & 3;
    int hi = high_idx[t], lo = low_idx[t];
    int sim1_lo = ssim[b*F_ + lo];
    int sim2_lo = ssim[80 + b*F_ + lo];
    int sim2_hi = ssim[80 + b*F_ + hi];
    rp_row[t] = sim1_lo;
    rn_row[t] = sim2_lo;
    outp[OUT_TAIL      + q*4 + b] = (float)sim2_hi; // high_sim, order (q,b)
    outp[OUT_TAIL + 16 + q*4 + b] = (float)sim1_lo; // low_sim
  }
}

// K7: write Rp and Rn (320 frames x 81920), uniform branch per block on replaced frames
__global__ void k_write(const float* __restrict__ x, const float* __restrict__ inv_norm,
                        const float* __restrict__ mem1, const float* __restrict__ mem2,
                        const int* __restrict__ high_idx, const int* __restrict__ low_idx,
                        const int* __restrict__ rp_row, const int* __restrict__ rn_row,
                        float* __restrict__ outp){
  int bid = blockIdx.x;          // 0..25599
  int fid = bid / 80;            // (q*4+b)*20+f
  int sub = bid % 80;
  int q = fid / 80;
  int rem = fid % 80;
  int b = rem / F_;
  int f = rem % F_;
  int t16 = b*4 + q;
  int lo = __ldg(low_idx + t16), hi = __ldg(high_idx + t16);
  int e4 = sub*256 + threadIdx.x;      // float4 index within frame, 0..20479
  int o = e4 >> 10;                    // object index
  float s = __ldg(inv_norm + (b*F_ + f)*OBJ + o);
  float4 xv = __ldg((const float4*)x + (size_t)(b*F_ + f)*FRAME_F4 + e4);
  float4 xn = f4scale(xv, s);
  float4 rp = xn, rn = xn;
  if (f == lo){
    int r = __ldg(rp_row + t16);
    rp = __ldg((const float4*)mem1 + (size_t)r*FRAME_F4 + e4);
  }
  if (f == hi){
    int r = __ldg(rn_row + t16);
    rn = __ldg((const float4*)mem2 + (size_t)r*FRAME_F4 + e4);
  }
  float4* o4 = (float4*)outp;
  size_t obase = (size_t)fid*FRAME_F4 + e4;
  o4[obase] = rp;
  o4[(RP_SZ/4) + obase] = rn;
}

extern "C" void kernel_launch(void* const* d_in, const int* in_sizes, int n_in,
                              void* d_out, int out_size, void* d_ws, size_t ws_size,
                              hipStream_t stream) {
  const float* qr       = (const float*)d_in[0]; // [4,4,20]
  const float* x        = (const float*)d_in[1]; // [4,20,20,4096]
  const float* mem1     = (const float*)d_in[2]; // [1000, 81920]
  const float* mem2     = (const float*)d_in[3];
  const int*   rand_idx = (const int*)  d_in[4]; // [4,4,1]
  float* outp = (float*)d_out;

  // ws layout (floats): mpn1 | mpn2 | rmaxn | inv_norm | pvals | pidx | idx arrays
  float* mpn1     = (float*)d_ws;              // 4,096,000
  float* mpn2     = mpn1 + 4096000;            // 4,096,000
  float* rmaxn    = mpn2 + 4096000;            // 327,680
  float* inv_norm = rmaxn + 327680;            // 1,600
  float* pvals    = inv_norm + 1600;           // 40,000
  int*   pidx     = (int*)(pvals + 40000);     // 40,000
  int*   high_idx = pidx + 40000;              // 16
  int*   low_idx  = high_idx + 16;             // 16
  int*   rp_row   = low_idx + 16;              // 16
  int*   rn_row   = rp_row + 16;               // 16  (total ~34.4 MB)

  k_norms<<<1600, 256, 0, stream>>>(x, inv_norm);
  k_memmp<<<2000, 256, 0, stream>>>(mem1, mem2, mpn1, mpn2);
  k_rmax <<<80,   256, 0, stream>>>(x, inv_norm, rmaxn);
  k_topk <<<1,    64,  0, stream>>>(qr, rand_idx, high_idx, low_idx);
  k_dots <<<500,  256, 0, stream>>>(mpn1, mpn2, rmaxn, pvals, pidx);
  k_finish<<<1,   256, 0, stream>>>(pvals, pidx, high_idx, low_idx, rp_row, rn_row, outp);
  k_write<<<25600,256, 0, stream>>>(x, inv_norm, mem1, mem2, high_idx, low_idx,
                                    rp_row, rn_row, outp);
}

// Round 2
// 935.316 us; speedup vs baseline: 1.1064x; 1.1064x over previous
//
#include <hip/hip_runtime.h>

// Problem constants
#define D 4096
#define OBJ 20
#define M_MEM 1000
#define F_ 20
// frames out = Q*B*F = 320; frame elems = OBJ*D = 81920 (=20480 float4)
// out layout: Rp [320*81920] | Rn [320*81920] | high_sim [16] | low_sim [16]
#define FRAME_F4 20480
#define RP_SZ 26214400
#define OUT_TAIL 52428800

__device__ __forceinline__ float4 f4max(float4 a, float4 b){
  return make_float4(fmaxf(a.x,b.x), fmaxf(a.y,b.y), fmaxf(a.z,b.z), fmaxf(a.w,b.w));
}
__device__ __forceinline__ float4 f4scale(float4 a, float s){
  return make_float4(a.x*s, a.y*s, a.z*s, a.w*s);
}
__device__ __forceinline__ double f4ss(float4 a){
  return (double)a.x*a.x + (double)a.y*a.y + (double)a.z*a.z + (double)a.w*a.w;
}

// monotone u32 key for float (handles negatives)
__device__ __forceinline__ unsigned int fkey(float f){
  unsigned int b = __float_as_uint(f);
  return (b & 0x80000000u) ? ~b : (b | 0x80000000u);
}

// 256-thread block sum reduce (f64), result broadcast to all threads
__device__ __forceinline__ double blockReduce256(double v){
  #pragma unroll
  for (int off = 32; off > 0; off >>= 1) v += __shfl_down(v, off, 64);
  __shared__ double sh[4];
  int w = threadIdx.x >> 6;
  if ((threadIdx.x & 63) == 0) sh[w] = v;
  __syncthreads();
  return sh[0] + sh[1] + sh[2] + sh[3];
}

// K1: inverse L2 norm of each (b,f,o) row of x  [1600 rows x 4096]
__global__ void k_norms(const float* __restrict__ x, float* __restrict__ inv_norm){
  int row = blockIdx.x;
  const float4* p = (const float4*)x + (size_t)row * 1024;
  double ss = 0.0;
  for (int i = threadIdx.x; i < 1024; i += 256){ float4 v = __ldg(p + i); ss += f4ss(v); }
  ss = blockReduce256(ss);
  if (threadIdx.x == 0) inv_norm[row] = (float)(1.0 / fmax(sqrt(ss), 1e-12));
}

// K2: R_max normalized rows [80 x 4096]
__global__ void k_rmax(const float* __restrict__ x, const float* __restrict__ inv_norm,
                       float* __restrict__ rmaxn){
  int bf = blockIdx.x; // 0..79
  __shared__ float sinv[OBJ];
  if (threadIdx.x < OBJ) sinv[threadIdx.x] = inv_norm[bf*OBJ + threadIdx.x];
  __syncthreads();
  float4 mv[4];
  #pragma unroll
  for (int i = 0; i < 4; i++) mv[i] = make_float4(-INFINITY,-INFINITY,-INFINITY,-INFINITY);
  const float4* base = (const float4*)x + (size_t)bf * OBJ * 1024;
  for (int o = 0; o < OBJ; o++){
    float s = sinv[o];
    const float4* p = base + o*1024;
    #pragma unroll
    for (int i = 0; i < 4; i++){
      float4 v = __ldg(p + threadIdx.x + i*256);
      mv[i] = f4max(mv[i], f4scale(v, s));
    }
  }
  double ss = 0.0;
  #pragma unroll
  for (int i = 0; i < 4; i++) ss += f4ss(mv[i]);
  ss = blockReduce256(ss);
  float rinv = (float)(1.0 / fmax(sqrt(ss), 1e-12));
  float4* outp = (float4*)rmaxn + (size_t)bf * 1024;
  #pragma unroll
  for (int i = 0; i < 4; i++) outp[threadIdx.x + i*256] = f4scale(mv[i], rinv);
}

// K3: mem max-pool over OBJ + L2 normalize -> mpn [1000 x 4096] each (the 655 MB stream)
__global__ void k_memmp(const float* __restrict__ mem1, const float* __restrict__ mem2,
                        float* __restrict__ out1, float* __restrict__ out2){
  int blk = blockIdx.x; // 0..1999
  const float* mem; float* outp; int m;
  if (blk < M_MEM){ mem = mem1; outp = out1; m = blk; }
  else            { mem = mem2; outp = out2; m = blk - M_MEM; }
  const float4* base = (const float4*)mem + (size_t)m * FRAME_F4;
  float4 mv[4];
  #pragma unroll
  for (int i = 0; i < 4; i++) mv[i] = make_float4(-INFINITY,-INFINITY,-INFINITY,-INFINITY);
  for (int o = 0; o < OBJ; o++){
    const float4* p = base + o*1024;
    #pragma unroll
    for (int i = 0; i < 4; i++) mv[i] = f4max(mv[i], __ldg(p + threadIdx.x + i*256));
  }
  double ss = 0.0;
  #pragma unroll
  for (int i = 0; i < 4; i++) ss += f4ss(mv[i]);
  ss = blockReduce256(ss);
  float rinv = (float)(1.0 / fmax(sqrt(ss), 1e-12));
  float4* o4 = (float4*)outp + (size_t)m * 1024;
  #pragma unroll
  for (int i = 0; i < 4; i++) o4[threadIdx.x + i*256] = f4scale(mv[i], rinv);
}

// K4: per (b,q): argmax frame (high) + rand-th smallest among rest (low); zero packed[]
__global__ void k_sel(const float* __restrict__ qr, const int* __restrict__ rand_idx,
                      int* __restrict__ high_idx, int* __restrict__ low_idx,
                      unsigned long long* __restrict__ packed){
  int t = threadIdx.x;
  if (t < 160) packed[t] = 0ull;
  if (t >= 16) return;
  float w[F_];
  for (int f = 0; f < F_; f++) w[f] = qr[t*F_ + f];
  int hi = 0; float hv = w[0];
  for (int f = 1; f < F_; f++) if (w[f] > hv){ hv = w[f]; hi = f; }
  int r = rand_idx[t];
  bool used[F_];
  for (int f = 0; f < F_; f++) used[f] = false;
  used[hi] = true;
  int li = 0;
  for (int it = 0; it <= r; it++){
    int bi = -1; float bv = INFINITY;
    for (int f = 0; f < F_; f++) if (!used[f] && w[f] < bv){ bv = w[f]; bi = f; }
    used[bi] = true; li = bi;
  }
  high_idx[t] = hi; low_idx[t] = li;
}

// K5: dots of 80 rmaxn rows vs 4 mem_mpn rows (LDS-staged), fp32 4-way-ILP acc,
//     winner published via atomicMax on packed (key<<32|idx)
__global__ void k_dots(const float* __restrict__ mpn1, const float* __restrict__ mpn2,
                       const float* __restrict__ rmaxn,
                       unsigned long long* __restrict__ packed){
  int blk = blockIdx.x;         // 0..499
  int which = blk / 250;        // 0 -> mem1, 1 -> mem2
  int chunk = blk % 250;        // 4 m-rows per chunk
  const float* mpn = which ? mpn2 : mpn1;
  __shared__ float4 rows[4*1024];   // 64 KB
  __shared__ float pv[4][80];
  const float4* src = (const float4*)mpn + (size_t)chunk * 4 * 1024;
  for (int i = threadIdx.x; i < 4096; i += 256) rows[i] = __ldg(src + i);
  __syncthreads();
  int w = threadIdx.x >> 6, lane = threadIdx.x & 63;
  const float4* mrow = rows + w*1024;
  for (int bf = 0; bf < 80; bf++){
    const float4* rrow = (const float4*)rmaxn + (size_t)bf * 1024;
    float ax = 0.f, ay = 0.f, az = 0.f, aw = 0.f;
    #pragma unroll
    for (int i = 0; i < 16; i++){
      float4 r = __ldg(rrow + i*64 + lane);
      float4 m = mrow[i*64 + lane];
      ax += r.x*m.x; ay += r.y*m.y; az += r.z*m.z; aw += r.w*m.w;
    }
    float s = (ax + ay) + (az + aw);
    #pragma unroll
    for (int off = 32; off > 0; off >>= 1) s += __shfl_down(s, off, 64);
    if (lane == 0) pv[w][bf] = s;
  }
  __syncthreads();
  if (threadIdx.x < 80){
    int bf = threadIdx.x;
    float best = pv[0][bf]; int bw = 0;
    #pragma unroll
    for (int w2 = 1; w2 < 4; w2++){ float v = pv[w2][bf]; if (v > best){ best = v; bw = w2; } }
    unsigned long long pk = ((unsigned long long)fkey(best) << 32) |
                            (unsigned int)(chunk*4 + bw);
    atomicMax(packed + which*80 + bf, pk);
  }
}

// K6: finalize — read packed winners, derive per-(b,q) memory rows + index outputs
__global__ void k_fin(const unsigned long long* __restrict__ packed,
                      const int* __restrict__ high_idx, const int* __restrict__ low_idx,
                      int* __restrict__ rp_row, int* __restrict__ rn_row,
                      float* __restrict__ outp){
  int t = threadIdx.x;
  if (t >= 16) return; // t = b*4+q
  int b = t >> 2, q = t & 3;
  int hi = high_idx[t], lo = low_idx[t];
  int sim1_lo = (int)(unsigned int)packed[      b*F_ + lo];
  int sim2_lo = (int)(unsigned int)packed[80 + b*F_ + lo];
  int sim2_hi = (int)(unsigned int)packed[80 + b*F_ + hi];
  rp_row[t] = sim1_lo;
  rn_row[t] = sim2_lo;
  outp[OUT_TAIL      + q*4 + b] = (float)sim2_hi; // high_sim, order (q,b)
  outp[OUT_TAIL + 16 + q*4 + b] = (float)sim1_lo; // low_sim
}

// K7: write Rp and Rn (320 frames x 81920); 8 blocks/frame, 10 float4/thread
__global__ void k_write(const float* __restrict__ x, const float* __restrict__ inv_norm,
                        const float* __restrict__ mem1, const float* __restrict__ mem2,
                        const int* __restrict__ high_idx, const int* __restrict__ low_idx,
                        const int* __restrict__ rp_row, const int* __restrict__ rn_row,
                        float* __restrict__ outp){
  int bid = blockIdx.x;          // 0..2559
  int fid = bid >> 3;            // (q*4+b)*20+f, 0..319
  int part = bid & 7;
  int q = fid / 80;
  int rem = fid % 80;
  int b = rem / F_;
  int f = rem % F_;
  int t16 = b*4 + q;
  int lo = __ldg(low_idx + t16), hi = __ldg(high_idx + t16);
  bool isLo = (f == lo), isHi = (f == hi);
  const float4* xf   = (const float4*)x + (size_t)(b*F_ + f)*FRAME_F4;
  const float*  invn = inv_norm + (b*F_ + f)*OBJ;
  const float4* m1p  = (const float4*)mem1 + (size_t)__ldg(rp_row + t16)*FRAME_F4;
  const float4* m2p  = (const float4*)mem2 + (size_t)__ldg(rn_row + t16)*FRAME_F4;
  float4* o4 = (float4*)outp;
  size_t fbase = (size_t)fid * FRAME_F4;
  #pragma unroll
  for (int k = 0; k < 10; k++){
    int e4 = part*2560 + k*256 + threadIdx.x;  // 0..20479
    int o = e4 >> 10;
    float s = __ldg(invn + o);
    float4 xn = f4scale(__ldg(xf + e4), s);
    float4 rp = isLo ? __ldg(m1p + e4) : xn;
    float4 rn = isHi ? __ldg(m2p + e4) : xn;
    o4[fbase + e4] = rp;
    o4[(RP_SZ/4) + fbase + e4] = rn;
  }
}

extern "C" void kernel_launch(void* const* d_in, const int* in_sizes, int n_in,
                              void* d_out, int out_size, void* d_ws, size_t ws_size,
                              hipStream_t stream) {
  const float* qr       = (const float*)d_in[0]; // [4,4,20]
  const float* x        = (const float*)d_in[1]; // [4,20,20,4096]
  const float* mem1     = (const float*)d_in[2]; // [1000, 81920]
  const float* mem2     = (const float*)d_in[3];
  const int*   rand_idx = (const int*)  d_in[4]; // [4,4,1]
  float* outp = (float*)d_out;

  // ws layout (floats): mpn1 | mpn2 | rmaxn | inv_norm | packed | idx arrays
  float* mpn1     = (float*)d_ws;                       // 4,096,000
  float* mpn2     = mpn1 + 4096000;                     // 4,096,000
  float* rmaxn    = mpn2 + 4096000;                     // 327,680
  float* inv_norm = rmaxn + 327680;                     // 1,600
  unsigned long long* packed = (unsigned long long*)(inv_norm + 1600); // 160 u64
  int*   high_idx = (int*)(packed + 160);               // 16
  int*   low_idx  = high_idx + 16;                      // 16
  int*   rp_row   = low_idx + 16;                       // 16
  int*   rn_row   = rp_row + 16;                        // 16

  k_norms<<<1600, 256, 0, stream>>>(x, inv_norm);
  k_memmp<<<2000, 256, 0, stream>>>(mem1, mem2, mpn1, mpn2);
  k_rmax <<<80,   256, 0, stream>>>(x, inv_norm, rmaxn);
  k_sel  <<<1,    192, 0, stream>>>(qr, rand_idx, high_idx, low_idx, packed);
  k_dots <<<500,  256, 0, stream>>>(mpn1, mpn2, rmaxn, packed);
  k_fin  <<<1,    64,  0, stream>>>(packed, high_idx, low_idx, rp_row, rn_row, outp);
  k_write<<<2560, 256, 0, stream>>>(x, inv_norm, mem1, mem2, high_idx, low_idx,
                                    rp_row, rn_row, outp);
}